// Round 9
// baseline (1044.893 us; speedup 1.0000x reference)
//
#include <hip/hip_runtime.h>
#include <hip/hip_bf16.h>

#define E    512
#define H    8
#define HD   64
#define TGT  512
#define SRC  2048
#define S1   2049
#define S1P  2112     // padded source length (33 chunks of 64)
#define NB   16
#define BH   128
#define NCH  33
#define PW   2120     // P row stride in shorts: 4240 B = 16B-aligned, bank-uniform

typedef __attribute__((ext_vector_type(8))) short short8;
typedef __attribute__((ext_vector_type(4))) float floatx4;

__device__ __forceinline__ unsigned short f2bf(float x) {
    unsigned u = __float_as_uint(x);
    u = (u + 0x7FFF + ((u >> 16) & 1)) >> 16;   // round-to-nearest-even
    return (unsigned short)u;
}

// single fp32 -> bf16 RNE via hardware cvt
__device__ __forceinline__ unsigned short f2bf1(float x) {
    __hip_bfloat16 h = __float2bfloat16(x);
    return *(unsigned short*)&h;
}

// pack 8 fp32 -> 8 bf16 (RNE) via compiler-fused v_cvt_pk_bf16_f32
__device__ __forceinline__ int4 cvt8(const float4 f0, const float4 f1) {
    __hip_bfloat162 o[4];
    o[0] = __float22bfloat162_rn({f0.x, f0.y});
    o[1] = __float22bfloat162_rn({f0.z, f0.w});
    o[2] = __float22bfloat162_rn({f1.x, f1.y});
    o[3] = __float22bfloat162_rn({f1.z, f1.w});
    return *(int4*)o;
}

// ---------------------------------------------------------------------------
// fp32 -> bf16 conversion, 8 elements/thread (packed cvt_pk) — weights only
// ---------------------------------------------------------------------------
__global__ __launch_bounds__(256) void cvt_bf16(const float* __restrict__ src,
    unsigned short* __restrict__ dst, const int n8)
{
    const int i = blockIdx.x * 256 + threadIdx.x;
    if (i >= n8) return;
    const float4 f0 = ((const float4*)src)[(size_t)i * 2];
    const float4 f1 = ((const float4*)src)[(size_t)i * 2 + 1];
    ((int4*)dst)[i] = cvt8(f0, f1);
}

// ---------------------------------------------------------------------------
// merged in-projection for q/k/v (blockIdx.z selects input/output).
// A-operand read directly as fp32 and converted during LDS staging (packed
// cvt_pk) — removes the 3 standalone q/k/v cvt kernels (226 MB + 3 launches).
//   z=0: q -> qbh [bh][t][hd], scaled 0.125 (only 64 y-blocks)
//   z=1: k -> kbuf [bh][s][hd] (ld = S1P)
//   z=2: v -> vtbuf [bh][hd][s] TRANSPOSED via LDS re-stage in the epilogue
// ---------------------------------------------------------------------------
__global__ __launch_bounds__(256) void proj_all(
    const float* __restrict__ query, const float* __restrict__ key,
    const float* __restrict__ value, const unsigned short* __restrict__ wi,
    const float* __restrict__ ipb,
    unsigned short* __restrict__ qbh, unsigned short* __restrict__ kbuf,
    unsigned short* __restrict__ vtbuf)
{
    const int z = blockIdx.z;
    if (z == 0 && blockIdx.y >= 64) return;
    __shared__ __align__(16) unsigned short As[128][72];
    __shared__ __align__(16) unsigned short Bs[64][72];
    const float* X = (z == 0) ? query : (z == 1) ? key : value;
    const unsigned short* W = wi + (size_t)z * 262144;
    const float* bias = ipb + z * E;
    const int tid  = threadIdx.x;
    const int c0   = blockIdx.x << 6;
    const int r0   = blockIdx.y << 7;
    const int w    = tid >> 6, lane = tid & 63, c = lane & 15, quad = lane >> 4;
    floatx4 acc[2][4] = {};
    for (int k0 = 0; k0 < E; k0 += 64) {
#pragma unroll
        for (int i = 0; i < 4; ++i) {
            const int idx = tid + (i << 8);
            const int r = idx >> 3, q = (idx & 7) << 3;
            const float4 f0 = *(const float4*)&X[(size_t)(r0 + r) * E + k0 + q];
            const float4 f1 = *(const float4*)&X[(size_t)(r0 + r) * E + k0 + q + 4];
            *(int4*)&As[r][q] = cvt8(f0, f1);
        }
#pragma unroll
        for (int i = 0; i < 2; ++i) {
            const int idx = tid + (i << 8);
            const int r = idx >> 3, q = (idx & 7) << 3;
            *(int4*)&Bs[r][q] = *(const int4*)&W[(size_t)(c0 + r) * E + k0 + q];
        }
        __syncthreads();
#pragma unroll
        for (int kh = 0; kh < 2; ++kh) {
            short8 a0 = *(const short8*)&As[(w << 5) + c][(kh << 5) + (quad << 3)];
            short8 a1 = *(const short8*)&As[(w << 5) + 16 + c][(kh << 5) + (quad << 3)];
#pragma unroll
            for (int n = 0; n < 4; ++n) {
                short8 b = *(const short8*)&Bs[(n << 4) + c][(kh << 5) + (quad << 3)];
                acc[0][n] = __builtin_amdgcn_mfma_f32_16x16x32_bf16(a0, b, acc[0][n], 0, 0, 0);
                acc[1][n] = __builtin_amdgcn_mfma_f32_16x16x32_bf16(a1, b, acc[1][n], 0, 0, 0);
            }
        }
        __syncthreads();
    }
    if (z == 2) {
        // ---- transposed epilogue: acc tile -> As (bf16), then each thread
        // gathers 8 consecutive s for one (b,hd) -> single int4 store ----
        const int h = c0 >> 6;
#pragma unroll
        for (int mt = 0; mt < 2; ++mt) {
#pragma unroll
            for (int reg = 0; reg < 4; ++reg) {
                const int local = (w << 5) + (mt << 4) + (quad << 2) + reg;
#pragma unroll
                for (int n = 0; n < 4; ++n) {
                    const int hd = (n << 4) + c;
                    As[local][hd] = f2bf1(acc[mt][n][reg] + bias[c0 + hd]);
                }
            }
        }
        __syncthreads();
        const int s0v = blockIdx.y << 3;       // rows rg: s = s0v + j, b = rg&15
#pragma unroll
        for (int i = 0; i < 4; ++i) {
            const int idx = tid + (i << 8);    // 0..1023
            const int b = idx & 15, hd = idx >> 4;
            unsigned short tmp[8];
#pragma unroll
            for (int j = 0; j < 8; ++j) tmp[j] = As[(j << 4) + b][hd];
            *(int4*)&vtbuf[((size_t)(b * H + h) * HD + hd) * S1P + s0v] = *(int4*)tmp;
        }
        return;
    }
    unsigned short* Y = (z == 0) ? qbh : kbuf;
    const int ld = (z == 0) ? TGT : S1P;
    const float scale = (z == 0) ? 0.125f : 1.0f;
#pragma unroll
    for (int mt = 0; mt < 2; ++mt) {
#pragma unroll
        for (int reg = 0; reg < 4; ++reg) {
            const int rg = r0 + (w << 5) + (mt << 4) + (quad << 2) + reg;
            const int t = rg >> 4, b = rg & 15;
#pragma unroll
            for (int n = 0; n < 4; ++n) {
                const int col = c0 + (n << 4) + c;
                const int h = col >> 6, hd = col & 63;
                const float v = (acc[mt][n][reg] + bias[col]) * scale;
                Y[((size_t)(b * H + h) * ld + t) * HD + hd] = f2bf1(v);
            }
        }
    }
}

// ---------------------------------------------------------------------------
// bias columns + pad-tail zeroing, fully parallel (one store per thread).
// ---------------------------------------------------------------------------
#define FB_BIAS  8192
#define FB_KPAD  64512                       // 128 bh * 504 int4 (63 rows * 64 hd)
#define FB_VPAD  516096                      // 128 bh * 64 hd * 63 s
__global__ __launch_bounds__(256) void fill_bias(const float* __restrict__ bk,
    const float* __restrict__ bv,
    unsigned short* __restrict__ kbuf, unsigned short* __restrict__ vtbuf)
{
    const int idx = blockIdx.x * 256 + threadIdx.x;
    if (idx < FB_BIAS) {
        const int bh = idx >> 6, hd = idx & 63, h = bh & 7;
        kbuf[((size_t)bh * S1P + SRC) * HD + hd] = f2bf(bk[h * HD + hd]);
        vtbuf[((size_t)bh * HD + hd) * S1P + SRC] = f2bf(bv[h * HD + hd]);
    } else if (idx < FB_BIAS + FB_KPAD) {
        const int i = idx - FB_BIAS;
        const int bh = i / 504, o = i % 504;
        const int4 z = {0, 0, 0, 0};
        ((int4*)&kbuf[((size_t)bh * S1P + S1) * HD])[o] = z;
    } else if (idx < FB_BIAS + FB_KPAD + FB_VPAD) {
        const int i = idx - FB_BIAS - FB_KPAD;
        const int bh = i / 4032, r = i % 4032;
        const int hd = r / 63, s = S1 + r % 63;
        vtbuf[((size_t)bh * HD + hd) * S1P + s] = 0;
    }
}

// ---------------------------------------------------------------------------
// Fused single-pass attention — R7/R8 configuration (best measured):
// 512 threads / 8 waves / 2 blocks per CU, no xcd swizzle,
// rolled prefetch depth 1 with asm register pin (anti-sink).
// ---------------------------------------------------------------------------
__global__ __launch_bounds__(512, 4) void attn_fused(
    const unsigned short* __restrict__ qbh,
    const unsigned short* __restrict__ kbuf,
    const unsigned short* __restrict__ vtbuf,
    const int* __restrict__ kpm,
    float* __restrict__ attn, unsigned short* __restrict__ ctx)
{
    __shared__ __align__(16) unsigned short P[16][PW];   // 67.84 KB
    __shared__ float cpart[16][68];                      // 4.25 KB
    __shared__ float sums[8][16];
    __shared__ float linv[16];
    const int tid = threadIdx.x;
    const int t0  = blockIdx.x << 4;
    const int bh  = blockIdx.y;
    const int bb  = bh >> 3;
    const int w = tid >> 6, lane = tid & 63, c = lane & 15, quad = lane >> 4;

    // Q A-fragments for this block's 16 rows (same for every wave)
    const unsigned short* qr = &qbh[((size_t)bh * TGT + t0 + c) * HD + (quad << 3)];
    short8 qa0 = *(const short8*)qr;
    short8 qa1 = *(const short8*)(qr + 32);

#define LOADK(D0, D1, M, CH) do {                                               \
        const unsigned short* kb_ = &kbuf[((size_t)bh * S1P + ((CH) << 6)) * HD]; \
        _Pragma("unroll")                                                       \
        for (int n_ = 0; n_ < 4; ++n_) {                                        \
            const unsigned short* kr_ = kb_ + ((n_ << 4) + c) * HD + (quad << 3); \
            D0[n_] = *(const short8*)kr_;                                       \
            D1[n_] = *(const short8*)(kr_ + 32);                                \
        }                                                                       \
        _Pragma("unroll")                                                       \
        for (int n_ = 0; n_ < 4; ++n_) {                                        \
            const int s_ = ((CH) << 6) + (n_ << 4) + c;                         \
            M[n_] = (s_ < SRC) ? (kpm[bb * SRC + s_] ? 3e38f : 0.f)             \
                               : ((s_ == SRC) ? 0.f : 3e38f);                   \
        }                                                                       \
    } while (0)

// force the prefetched fragments to be materialized HERE (anti-sink)
#define PIN(D0, D1) asm volatile("" :                                          \
        "+v"(D0[0]), "+v"(D0[1]), "+v"(D0[2]), "+v"(D0[3]),                     \
        "+v"(D1[0]), "+v"(D1[1]), "+v"(D1[2]), "+v"(D1[3]))

#define QK_COMPUTE(CH, B0, B1, M) do {                                          \
        const int s0_ = (CH) << 6;                                              \
        floatx4 sc_[4] = {};                                                    \
        _Pragma("unroll")                                                       \
        for (int n_ = 0; n_ < 4; ++n_) {                                        \
            sc_[n_] = __builtin_amdgcn_mfma_f32_16x16x32_bf16(qa0, B0[n_], sc_[n_], 0, 0, 0); \
            sc_[n_] = __builtin_amdgcn_mfma_f32_16x16x32_bf16(qa1, B1[n_], sc_[n_], 0, 0, 0); \
        }                                                                       \
        _Pragma("unroll")                                                       \
        for (int n_ = 0; n_ < 4; ++n_) {                                        \
            _Pragma("unroll")                                                   \
            for (int rg_ = 0; rg_ < 4; ++rg_) {                                 \
                const float p_ = __expf(sc_[n_][rg_] - M[n_]);                  \
                rs[rg_] += p_;                                                  \
                P[(quad << 2) + rg_][s0_ + (n_ << 4) + c] = f2bf1(p_);          \
            }                                                                   \
        }                                                                       \
    } while (0)

    // ---- phase 1: QK^T + exp, 33 chunks over 8 waves, prefetch depth 1 ----
    float rs[4] = {0.f, 0.f, 0.f, 0.f};
    short8 kb0[4], kb1[4];
    float mk[4];
    LOADK(kb0, kb1, mk, w);
    int ch;
    for (ch = w; ch + 8 < NCH; ch += 8) {
        short8 nb0[4], nb1[4];
        float nm[4];
        LOADK(nb0, nb1, nm, ch + 8);
        PIN(nb0, nb1);                        // loads issued before compute
        QK_COMPUTE(ch, kb0, kb1, mk);
#pragma unroll
        for (int n = 0; n < 4; ++n) { kb0[n] = nb0[n]; kb1[n] = nb1[n]; mk[n] = nm[n]; }
    }
    QK_COMPUTE(ch, kb0, kb1, mk);

    // ---- phase 2: row-sum reduction (over c lanes, then over 8 waves) ----
#pragma unroll
    for (int reg = 0; reg < 4; ++reg) {
        float v = rs[reg];
        v += __shfl_xor(v, 1); v += __shfl_xor(v, 2);
        v += __shfl_xor(v, 4); v += __shfl_xor(v, 8);
        rs[reg] = v;
    }
    if (c == 0) {
#pragma unroll
        for (int reg = 0; reg < 4; ++reg)
            sums[w][(quad << 2) + reg] = rs[reg];
    }
    __syncthreads();
    if (tid < 16) {
        float s = 0.f;
#pragma unroll
        for (int i = 0; i < 8; ++i) s += sums[i][tid];
        linv[tid] = 1.0f / s;
    }
    __syncthreads();

    // ---- phase 3a: PV. wave -> (hd-slice hs, K-half kh2); 33 units of 32
    // columns per half; V prefetch depth 4, tail unit loaded first. ----
    const int hs = w & 3, kh2 = w >> 2;
    const int base = kh2 * 1056;
    const unsigned short* vrow = &vtbuf[((size_t)bh * HD + (hs << 4) + c) * S1P + base];
#define LV(U) (*(const short8*)&vrow[((U) << 5) + (quad << 3)])
#define LP(U) (*(const short8*)&P[c][base + ((U) << 5) + (quad << 3)])
    floatx4 ca0 = {}, ca1 = {};
    short8 vt = LV(32);
    short8 v0 = LV(0), v1 = LV(1), v2 = LV(2), v3 = LV(3);
#pragma unroll
    for (int u = 0; u < 32; u += 4) {
        ca0 = __builtin_amdgcn_mfma_f32_16x16x32_bf16(LP(u),     v0, ca0, 0, 0, 0);
        ca1 = __builtin_amdgcn_mfma_f32_16x16x32_bf16(LP(u + 1), v1, ca1, 0, 0, 0);
        if (u < 28) { v0 = LV(u + 4); v1 = LV(u + 5); }
        ca0 = __builtin_amdgcn_mfma_f32_16x16x32_bf16(LP(u + 2), v2, ca0, 0, 0, 0);
        ca1 = __builtin_amdgcn_mfma_f32_16x16x32_bf16(LP(u + 3), v3, ca1, 0, 0, 0);
        if (u < 28) { v2 = LV(u + 6); v3 = LV(u + 7); }
    }
    ca0 = __builtin_amdgcn_mfma_f32_16x16x32_bf16(LP(32), vt, ca0, 0, 0, 0);
    if (kh2 == 1) {
#pragma unroll
        for (int reg = 0; reg < 4; ++reg)
            cpart[(quad << 2) + reg][(hs << 4) + c] = ca0[reg] + ca1[reg];
    }
    __syncthreads();
    if (kh2 == 0) {
#pragma unroll
        for (int reg = 0; reg < 4; ++reg) {
            const int row = (quad << 2) + reg;
            const float v = (ca0[reg] + ca1[reg] + cpart[row][(hs << 4) + c]) * linv[row];
            ctx[((size_t)bh * TGT + t0 + row) * HD + (hs << 4) + c] = f2bf1(v);
        }
    }

    // ---- phase 3b: normalized fp32 attn stores. 16 pairs of 64-col chunks
    // over 8 waves; each lane reads 2 P values per b32 LDS read. ----
    for (int p = w; p < 16; p += 8) {
        const int s0 = p << 7;
#pragma unroll
        for (int r = 0; r < 16; ++r) {
            const unsigned pk = *(const unsigned*)&P[r][s0 + (lane << 1)];
            const float li = linv[r];
            const size_t a = ((size_t)bh * TGT + t0 + r) * S1 + s0 + (lane << 1);
            attn[a]     = __uint_as_float((pk & 0xFFFFu) << 16) * li;
            attn[a + 1] = __uint_as_float(pk & 0xFFFF0000u) * li;
        }
    }
    if (w == 7 && lane < 16) {   // last real column s == 2048
        const float p = __uint_as_float((unsigned)P[lane][2048] << 16) * linv[lane];
        attn[((size_t)bh * TGT + t0 + lane) * S1 + 2048] = p;
    }
#undef LOADK
#undef PIN
#undef QK_COMPUTE
#undef LV
#undef LP
}

// ---------------------------------------------------------------------------
// out-projection: out[r][e] = ctx_row(r) . W[e][:] + bias[e]  (fp32 out)
// ---------------------------------------------------------------------------
__global__ __launch_bounds__(256) void outproj_gemm(const unsigned short* __restrict__ ctx,
    const unsigned short* __restrict__ W, const float* __restrict__ bias,
    float* __restrict__ out)
{
    __shared__ __align__(16) unsigned short As[128][72];
    __shared__ __align__(16) unsigned short Bs[64][72];
    const int tid = threadIdx.x;
    const int c0  = blockIdx.x << 6;
    const int r0  = blockIdx.y << 7;
    const int w   = tid >> 6, lane = tid & 63, c = lane & 15, quad = lane >> 4;
    floatx4 acc[2][4] = {};
    for (int k0 = 0; k0 < E; k0 += 64) {
        const int h = k0 >> 6;
#pragma unroll
        for (int i = 0; i < 4; ++i) {
            const int idx = tid + (i << 8);
            const int r = idx >> 3, q = (idx & 7) << 3;
            const int rg = r0 + r, t = rg >> 4, b = rg & 15;
            *(int4*)&As[r][q] = *(const int4*)&ctx[((size_t)(b * H + h) * TGT + t) * HD + q];
        }
#pragma unroll
        for (int i = 0; i < 2; ++i) {
            const int idx = tid + (i << 8);
            const int r = idx >> 3, q = (idx & 7) << 3;
            *(int4*)&Bs[r][q] = *(const int4*)&W[(size_t)(c0 + r) * E + k0 + q];
        }
        __syncthreads();
#pragma unroll
        for (int kh = 0; kh < 2; ++kh) {
            short8 a0 = *(const short8*)&As[(w << 5) + c][(kh << 5) + (quad << 3)];
            short8 a1 = *(const short8*)&As[(w << 5) + 16 + c][(kh << 5) + (quad << 3)];
#pragma unroll
            for (int n = 0; n < 4; ++n) {
                short8 b = *(const short8*)&Bs[(n << 4) + c][(kh << 5) + (quad << 3)];
                acc[0][n] = __builtin_amdgcn_mfma_f32_16x16x32_bf16(a0, b, acc[0][n], 0, 0, 0);
                acc[1][n] = __builtin_amdgcn_mfma_f32_16x16x32_bf16(a1, b, acc[1][n], 0, 0, 0);
            }
        }
        __syncthreads();
    }
#pragma unroll
    for (int mt = 0; mt < 2; ++mt) {
#pragma unroll
        for (int reg = 0; reg < 4; ++reg) {
            const int rg = r0 + (w << 5) + (mt << 4) + (quad << 2) + reg;
#pragma unroll
            for (int n = 0; n < 4; ++n) {
                const int col = c0 + (n << 4) + c;
                out[(size_t)rg * E + col] = acc[mt][n][reg] + bias[col];
            }
        }
    }
}

extern "C" void kernel_launch(void* const* d_in, const int* in_sizes, int n_in,
                              void* d_out, int out_size, void* d_ws, size_t ws_size,
                              hipStream_t stream)
{
    const float* query  = (const float*)d_in[0];
    const float* key    = (const float*)d_in[1];
    const float* value  = (const float*)d_in[2];
    const float* ipw    = (const float*)d_in[3];
    const float* ipb    = (const float*)d_in[4];
    const float* bias_k = (const float*)d_in[5];
    const float* bias_v = (const float*)d_in[6];
    const float* opw    = (const float*)d_in[7];
    const float* opb    = (const float*)d_in[8];
    const int*   kpm    = (const int*)d_in[9];

    float* out  = (float*)d_out;
    float* attn = out + (size_t)TGT * NB * E;                 // 128*512*2049 fp32

    char* ws = (char*)d_ws;
    unsigned short* wi_bf = (unsigned short*)ws;                       // [3E][E]
    unsigned short* wo_bf = wi_bf + (size_t)786432;                    // [E][E]
    unsigned short* qbh   = wo_bf + (size_t)262144;                    // [bh][t][hd]
    unsigned short* kbuf  = qbh   + (size_t)4194304;                   // [bh][S1P][hd]
    unsigned short* vtbuf = kbuf  + (size_t)17301504;                  // [bh][hd][S1P]
    unsigned short* ctx   = vtbuf + (size_t)17301504;                  // [bh][t][hd]

    cvt_bf16<<<dim3(384), 256, 0, stream>>>(ipw, wi_bf, 98304);
    cvt_bf16<<<dim3(128), 256, 0, stream>>>(opw, wo_bf, 32768);

    proj_all<<<dim3(8, 256, 3), 256, 0, stream>>>(query, key, value, wi_bf, ipb,
                                                  qbh, kbuf, vtbuf);

    fill_bias<<<dim3(2300), 256, 0, stream>>>(bias_k, bias_v, kbuf, vtbuf);

    attn_fused<<<dim3(32, 128), 512, 0, stream>>>(qbh, kbuf, vtbuf, kpm, attn, ctx);
    outproj_gemm<<<dim3(8, 64), 256, 0, stream>>>(ctx, wo_bf, opb, out);
}

// Round 10
// 1019.191 us; speedup vs baseline: 1.0252x; 1.0252x over previous
//
#include <hip/hip_runtime.h>
#include <hip/hip_bf16.h>

#define E    512
#define H    8
#define HD   64
#define TGT  512
#define SRC  2048
#define S1   2049
#define S1P  2112     // padded source length (33 chunks of 64)
#define NB   16
#define BH   128
#define NCH  33
#define PW   2120     // P row stride in shorts: 4240 B = 16B-aligned, bank-uniform

typedef __attribute__((ext_vector_type(8))) short short8;
typedef __attribute__((ext_vector_type(4))) float floatx4;

__device__ __forceinline__ unsigned short f2bf(float x) {
    unsigned u = __float_as_uint(x);
    u = (u + 0x7FFF + ((u >> 16) & 1)) >> 16;   // round-to-nearest-even
    return (unsigned short)u;
}

// single fp32 -> bf16 RNE via hardware cvt
__device__ __forceinline__ unsigned short f2bf1(float x) {
    __hip_bfloat16 h = __float2bfloat16(x);
    return *(unsigned short*)&h;
}

// pack 8 fp32 -> 8 bf16 (RNE) via compiler-fused v_cvt_pk_bf16_f32
__device__ __forceinline__ int4 cvt8(const float4 f0, const float4 f1) {
    __hip_bfloat162 o[4];
    o[0] = __float22bfloat162_rn({f0.x, f0.y});
    o[1] = __float22bfloat162_rn({f0.z, f0.w});
    o[2] = __float22bfloat162_rn({f1.x, f1.y});
    o[3] = __float22bfloat162_rn({f1.z, f1.w});
    return *(int4*)o;
}

// ---------------------------------------------------------------------------
// fp32 -> bf16 conversion, 8 elements/thread (packed cvt_pk)
// ---------------------------------------------------------------------------
__global__ __launch_bounds__(256) void cvt_bf16(const float* __restrict__ src,
    unsigned short* __restrict__ dst, const int n8)
{
    const int i = blockIdx.x * 256 + threadIdx.x;
    if (i >= n8) return;
    const float4 f0 = ((const float4*)src)[(size_t)i * 2];
    const float4 f1 = ((const float4*)src)[(size_t)i * 2 + 1];
    ((int4*)dst)[i] = cvt8(f0, f1);
}

// ---------------------------------------------------------------------------
// merged in-projection for q/k/v (blockIdx.z selects input/output), bf16 in.
//   z=0: q -> qbh [bh][t][hd], scaled 0.125 (only 64 y-blocks)
//   z=1: k -> kbuf [bh][s][hd] (ld = S1P)
//   z=2: v -> vtbuf [bh][hd][s] TRANSPOSED via LDS re-stage in the epilogue
// ---------------------------------------------------------------------------
__global__ __launch_bounds__(256) void proj_all(
    const unsigned short* __restrict__ q_bf, const unsigned short* __restrict__ k_bf,
    const unsigned short* __restrict__ v_bf, const unsigned short* __restrict__ wi,
    const float* __restrict__ ipb,
    unsigned short* __restrict__ qbh, unsigned short* __restrict__ kbuf,
    unsigned short* __restrict__ vtbuf)
{
    const int z = blockIdx.z;
    if (z == 0 && blockIdx.y >= 64) return;
    __shared__ __align__(16) unsigned short As[128][72];
    __shared__ __align__(16) unsigned short Bs[64][72];
    const unsigned short* X = (z == 0) ? q_bf : (z == 1) ? k_bf : v_bf;
    const unsigned short* W = wi + (size_t)z * 262144;
    const float* bias = ipb + z * E;
    const int tid  = threadIdx.x;
    const int c0   = blockIdx.x << 6;
    const int r0   = blockIdx.y << 7;
    const int w    = tid >> 6, lane = tid & 63, c = lane & 15, quad = lane >> 4;
    floatx4 acc[2][4] = {};
    for (int k0 = 0; k0 < E; k0 += 64) {
#pragma unroll
        for (int i = 0; i < 4; ++i) {
            const int idx = tid + (i << 8);
            const int r = idx >> 3, q = (idx & 7) << 3;
            *(int4*)&As[r][q] = *(const int4*)&X[(size_t)(r0 + r) * E + k0 + q];
        }
#pragma unroll
        for (int i = 0; i < 2; ++i) {
            const int idx = tid + (i << 8);
            const int r = idx >> 3, q = (idx & 7) << 3;
            *(int4*)&Bs[r][q] = *(const int4*)&W[(size_t)(c0 + r) * E + k0 + q];
        }
        __syncthreads();
#pragma unroll
        for (int kh = 0; kh < 2; ++kh) {
            short8 a0 = *(const short8*)&As[(w << 5) + c][(kh << 5) + (quad << 3)];
            short8 a1 = *(const short8*)&As[(w << 5) + 16 + c][(kh << 5) + (quad << 3)];
#pragma unroll
            for (int n = 0; n < 4; ++n) {
                short8 b = *(const short8*)&Bs[(n << 4) + c][(kh << 5) + (quad << 3)];
                acc[0][n] = __builtin_amdgcn_mfma_f32_16x16x32_bf16(a0, b, acc[0][n], 0, 0, 0);
                acc[1][n] = __builtin_amdgcn_mfma_f32_16x16x32_bf16(a1, b, acc[1][n], 0, 0, 0);
            }
        }
        __syncthreads();
    }
    if (z == 2) {
        // transposed epilogue: acc tile -> As (bf16), then each thread gathers
        // 8 consecutive s for one (b,hd) -> single int4 store
        const int h = c0 >> 6;
#pragma unroll
        for (int mt = 0; mt < 2; ++mt) {
#pragma unroll
            for (int reg = 0; reg < 4; ++reg) {
                const int local = (w << 5) + (mt << 4) + (quad << 2) + reg;
#pragma unroll
                for (int n = 0; n < 4; ++n) {
                    const int hd = (n << 4) + c;
                    As[local][hd] = f2bf1(acc[mt][n][reg] + bias[c0 + hd]);
                }
            }
        }
        __syncthreads();
        const int s0v = blockIdx.y << 3;
#pragma unroll
        for (int i = 0; i < 4; ++i) {
            const int idx = tid + (i << 8);
            const int b = idx & 15, hd = idx >> 4;
            unsigned short tmp[8];
#pragma unroll
            for (int j = 0; j < 8; ++j) tmp[j] = As[(j << 4) + b][hd];
            *(int4*)&vtbuf[((size_t)(b * H + h) * HD + hd) * S1P + s0v] = *(int4*)tmp;
        }
        return;
    }
    unsigned short* Y = (z == 0) ? qbh : kbuf;
    const int ld = (z == 0) ? TGT : S1P;
    const float scale = (z == 0) ? 0.125f : 1.0f;
#pragma unroll
    for (int mt = 0; mt < 2; ++mt) {
#pragma unroll
        for (int reg = 0; reg < 4; ++reg) {
            const int rg = r0 + (w << 5) + (mt << 4) + (quad << 2) + reg;
            const int t = rg >> 4, b = rg & 15;
#pragma unroll
            for (int n = 0; n < 4; ++n) {
                const int col = c0 + (n << 4) + c;
                const int h = col >> 6, hd = col & 63;
                const float v = (acc[mt][n][reg] + bias[col]) * scale;
                Y[((size_t)(b * H + h) * ld + t) * HD + hd] = f2bf1(v);
            }
        }
    }
}

// ---------------------------------------------------------------------------
// bias columns + pad-tail zeroing, fully parallel (one store per thread).
// ---------------------------------------------------------------------------
#define FB_BIAS  8192
#define FB_KPAD  64512                       // 128 bh * 504 int4 (63 rows * 64 hd)
#define FB_VPAD  516096                      // 128 bh * 64 hd * 63 s
__global__ __launch_bounds__(256) void fill_bias(const float* __restrict__ bk,
    const float* __restrict__ bv,
    unsigned short* __restrict__ kbuf, unsigned short* __restrict__ vtbuf)
{
    const int idx = blockIdx.x * 256 + threadIdx.x;
    if (idx < FB_BIAS) {
        const int bh = idx >> 6, hd = idx & 63, h = bh & 7;
        kbuf[((size_t)bh * S1P + SRC) * HD + hd] = f2bf(bk[h * HD + hd]);
        vtbuf[((size_t)bh * HD + hd) * S1P + SRC] = f2bf(bv[h * HD + hd]);
    } else if (idx < FB_BIAS + FB_KPAD) {
        const int i = idx - FB_BIAS;
        const int bh = i / 504, o = i % 504;
        const int4 z = {0, 0, 0, 0};
        ((int4*)&kbuf[((size_t)bh * S1P + S1) * HD])[o] = z;
    } else if (idx < FB_BIAS + FB_KPAD + FB_VPAD) {
        const int i = idx - FB_BIAS - FB_KPAD;
        const int bh = i / 4032, r = i % 4032;
        const int hd = r / 63, s = S1 + r % 63;
        vtbuf[((size_t)bh * HD + hd) * S1P + s] = 0;
    }
}

// ---------------------------------------------------------------------------
// Fused single-pass attention, QBLK=32: one block = 32 Q-rows of one (b,h),
// 1024 threads / 16 waves, P resident in 135.7 KB LDS, 1 block/CU.
// Rationale: kernel is invariant under ILP (R1), 2x TLP (R6) and HBM-FETCH
// reduction (R5) at ~355 us -> bound by total cache-hierarchy read volume
// (2.2 GB @ ~6.2 TB/s). Doubling rows/block halves K/V re-reads to 1.1 GB.
//  - phase 1: 33 chunks over 16 waves, both 16-row groups per chunk
//  - phase 2: cross-wave row-sum reduction -> linv[32]
//  - phase 3a: PV, wave = (row-half, hd-slice, K-half); V prefetch depth 4
//  - phase 3b: wave w stores col-block w of the normalized fp32 attn
// ---------------------------------------------------------------------------
__global__ __launch_bounds__(1024) void attn_fused(
    const unsigned short* __restrict__ qbh,
    const unsigned short* __restrict__ kbuf,
    const unsigned short* __restrict__ vtbuf,
    const int* __restrict__ kpm,
    float* __restrict__ attn, unsigned short* __restrict__ ctx)
{
    __shared__ __align__(16) unsigned short P[32][PW];   // 135.68 KB
    __shared__ float cpart[32][68];                      // 8.70 KB
    __shared__ float sums[16][32];                       // 2 KB
    __shared__ float linv[32];
    const int tid = threadIdx.x;
    const int t0  = blockIdx.x << 5;
    const int bh  = blockIdx.y;
    const int bb  = bh >> 3;
    const int w = tid >> 6, lane = tid & 63, c = lane & 15, quad = lane >> 4;

    // Q A-fragments for rows t0..t0+15 (qa) and t0+16..t0+31 (qb)
    const unsigned short* qr = &qbh[((size_t)bh * TGT + t0 + c) * HD + (quad << 3)];
    short8 qa0 = *(const short8*)qr;
    short8 qa1 = *(const short8*)(qr + 32);
    const unsigned short* qr2 = qr + (size_t)16 * HD;
    short8 qb0 = *(const short8*)qr2;
    short8 qb1 = *(const short8*)(qr2 + 32);

#define LOADK(CH) do {                                                          \
        const unsigned short* kb_ = &kbuf[((size_t)bh * S1P + ((CH) << 6)) * HD]; \
        _Pragma("unroll")                                                       \
        for (int n_ = 0; n_ < 4; ++n_) {                                        \
            const unsigned short* kr_ = kb_ + ((n_ << 4) + c) * HD + (quad << 3); \
            kb0[n_] = *(const short8*)kr_;                                      \
            kb1[n_] = *(const short8*)(kr_ + 32);                               \
        }                                                                       \
        _Pragma("unroll")                                                       \
        for (int n_ = 0; n_ < 4; ++n_) {                                        \
            const int s_ = ((CH) << 6) + (n_ << 4) + c;                         \
            mk[n_] = (s_ < SRC) ? (kpm[bb * SRC + s_] ? 3e38f : 0.f)            \
                                : ((s_ == SRC) ? 0.f : 3e38f);                  \
        }                                                                       \
    } while (0)

#define QK2(CH) do {                                                            \
        const int s0_ = (CH) << 6;                                              \
        floatx4 sc_[4] = {};                                                    \
        _Pragma("unroll")                                                       \
        for (int n_ = 0; n_ < 4; ++n_) {                                        \
            sc_[n_] = __builtin_amdgcn_mfma_f32_16x16x32_bf16(qa0, kb0[n_], sc_[n_], 0, 0, 0); \
            sc_[n_] = __builtin_amdgcn_mfma_f32_16x16x32_bf16(qa1, kb1[n_], sc_[n_], 0, 0, 0); \
        }                                                                       \
        _Pragma("unroll")                                                       \
        for (int n_ = 0; n_ < 4; ++n_) {                                        \
            _Pragma("unroll")                                                   \
            for (int rg_ = 0; rg_ < 4; ++rg_) {                                 \
                const float p_ = __expf(sc_[n_][rg_] - mk[n_]);                 \
                rs0[rg_] += p_;                                                 \
                P[(quad << 2) + rg_][s0_ + (n_ << 4) + c] = f2bf1(p_);          \
            }                                                                   \
        }                                                                       \
        floatx4 sd_[4] = {};                                                    \
        _Pragma("unroll")                                                       \
        for (int n_ = 0; n_ < 4; ++n_) {                                        \
            sd_[n_] = __builtin_amdgcn_mfma_f32_16x16x32_bf16(qb0, kb0[n_], sd_[n_], 0, 0, 0); \
            sd_[n_] = __builtin_amdgcn_mfma_f32_16x16x32_bf16(qb1, kb1[n_], sd_[n_], 0, 0, 0); \
        }                                                                       \
        _Pragma("unroll")                                                       \
        for (int n_ = 0; n_ < 4; ++n_) {                                        \
            _Pragma("unroll")                                                   \
            for (int rg_ = 0; rg_ < 4; ++rg_) {                                 \
                const float p_ = __expf(sd_[n_][rg_] - mk[n_]);                 \
                rs1[rg_] += p_;                                                 \
                P[16 + (quad << 2) + rg_][s0_ + (n_ << 4) + c] = f2bf1(p_);     \
            }                                                                   \
        }                                                                       \
    } while (0)

    // ---- phase 1: QK^T + exp, 33 chunks over 16 waves, 32 rows each ----
    float rs0[4] = {0.f, 0.f, 0.f, 0.f};
    float rs1[4] = {0.f, 0.f, 0.f, 0.f};
    short8 kb0[4], kb1[4];
    float mk[4];
    LOADK(w);
    QK2(w);
    LOADK(w + 16);
    QK2(w + 16);
    if (w == 0) {
        LOADK(32);
        QK2(32);
    }

    // ---- phase 2: row-sum reduction (over c lanes, then over 16 waves) ----
#pragma unroll
    for (int reg = 0; reg < 4; ++reg) {
        float v0s = rs0[reg], v1s = rs1[reg];
        v0s += __shfl_xor(v0s, 1); v0s += __shfl_xor(v0s, 2);
        v0s += __shfl_xor(v0s, 4); v0s += __shfl_xor(v0s, 8);
        v1s += __shfl_xor(v1s, 1); v1s += __shfl_xor(v1s, 2);
        v1s += __shfl_xor(v1s, 4); v1s += __shfl_xor(v1s, 8);
        rs0[reg] = v0s; rs1[reg] = v1s;
    }
    if (c == 0) {
#pragma unroll
        for (int reg = 0; reg < 4; ++reg) {
            sums[w][(quad << 2) + reg]      = rs0[reg];
            sums[w][16 + (quad << 2) + reg] = rs1[reg];
        }
    }
    __syncthreads();
    if (tid < 32) {
        float s = 0.f;
#pragma unroll
        for (int i = 0; i < 16; ++i) s += sums[i][tid];
        linv[tid] = 1.0f / s;
    }
    __syncthreads();

    // ---- phase 3a: PV. wave -> (row-half rh, hd-slice hs, K-half kh2) ----
    const int rh = w >> 3, hs = (w >> 1) & 3, kh2 = w & 1;
    const int base = kh2 * 1056;
    const unsigned short* vrow = &vtbuf[((size_t)bh * HD + (hs << 4) + c) * S1P + base];
#define LV(U) (*(const short8*)&vrow[((U) << 5) + (quad << 3)])
#define LP(U) (*(const short8*)&P[(rh << 4) + c][base + ((U) << 5) + (quad << 3)])
    floatx4 ca0 = {}, ca1 = {};
    short8 vt = LV(32);
    short8 v0 = LV(0), v1 = LV(1), v2 = LV(2), v3 = LV(3);
#pragma unroll
    for (int u = 0; u < 32; u += 4) {
        ca0 = __builtin_amdgcn_mfma_f32_16x16x32_bf16(LP(u),     v0, ca0, 0, 0, 0);
        ca1 = __builtin_amdgcn_mfma_f32_16x16x32_bf16(LP(u + 1), v1, ca1, 0, 0, 0);
        if (u < 28) { v0 = LV(u + 4); v1 = LV(u + 5); }
        ca0 = __builtin_amdgcn_mfma_f32_16x16x32_bf16(LP(u + 2), v2, ca0, 0, 0, 0);
        ca1 = __builtin_amdgcn_mfma_f32_16x16x32_bf16(LP(u + 3), v3, ca1, 0, 0, 0);
        if (u < 28) { v2 = LV(u + 6); v3 = LV(u + 7); }
    }
    ca0 = __builtin_amdgcn_mfma_f32_16x16x32_bf16(LP(32), vt, ca0, 0, 0, 0);
    if (kh2 == 1) {
#pragma unroll
        for (int reg = 0; reg < 4; ++reg)
            cpart[(rh << 4) + (quad << 2) + reg][(hs << 4) + c] = ca0[reg] + ca1[reg];
    }
    __syncthreads();
    if (kh2 == 0) {
#pragma unroll
        for (int reg = 0; reg < 4; ++reg) {
            const int row = (rh << 4) + (quad << 2) + reg;
            const float v = (ca0[reg] + ca1[reg] + cpart[row][(hs << 4) + c]) * linv[row];
            ctx[((size_t)bh * TGT + t0 + row) * HD + (hs << 4) + c] = f2bf1(v);
        }
    }

    // ---- phase 3b: normalized fp32 attn stores; wave w owns cols
    // [128w, 128w+128); each lane reads 2 P values per b32 LDS read. ----
    {
        const int s0 = w << 7;
#pragma unroll
        for (int r = 0; r < 32; ++r) {
            const unsigned pk = *(const unsigned*)&P[r][s0 + (lane << 1)];
            const float li = linv[r];
            const size_t a = ((size_t)bh * TGT + t0 + r) * S1 + s0 + (lane << 1);
            attn[a]     = __uint_as_float((pk & 0xFFFFu) << 16) * li;
            attn[a + 1] = __uint_as_float(pk & 0xFFFF0000u) * li;
        }
    }
    if (w == 15 && lane < 32) {   // last real column s == 2048
        const float p = __uint_as_float((unsigned)P[lane][2048] << 16) * linv[lane];
        attn[((size_t)bh * TGT + t0 + lane) * S1 + 2048] = p;
    }
#undef LOADK
#undef QK2
#undef LV
#undef LP
}

// ---------------------------------------------------------------------------
// out-projection: out[r][e] = ctx_row(r) . W[e][:] + bias[e]  (fp32 out)
// ---------------------------------------------------------------------------
__global__ __launch_bounds__(256) void outproj_gemm(const unsigned short* __restrict__ ctx,
    const unsigned short* __restrict__ W, const float* __restrict__ bias,
    float* __restrict__ out)
{
    __shared__ __align__(16) unsigned short As[128][72];
    __shared__ __align__(16) unsigned short Bs[64][72];
    const int tid = threadIdx.x;
    const int c0  = blockIdx.x << 6;
    const int r0  = blockIdx.y << 7;
    const int w   = tid >> 6, lane = tid & 63, c = lane & 15, quad = lane >> 4;
    floatx4 acc[2][4] = {};
    for (int k0 = 0; k0 < E; k0 += 64) {
        const int h = k0 >> 6;
#pragma unroll
        for (int i = 0; i < 4; ++i) {
            const int idx = tid + (i << 8);
            const int r = idx >> 3, q = (idx & 7) << 3;
            const int rg = r0 + r, t = rg >> 4, b = rg & 15;
            *(int4*)&As[r][q] = *(const int4*)&ctx[((size_t)(b * H + h) * TGT + t) * HD + q];
        }
#pragma unroll
        for (int i = 0; i < 2; ++i) {
            const int idx = tid + (i << 8);
            const int r = idx >> 3, q = (idx & 7) << 3;
            *(int4*)&Bs[r][q] = *(const int4*)&W[(size_t)(c0 + r) * E + k0 + q];
        }
        __syncthreads();
#pragma unroll
        for (int kh = 0; kh < 2; ++kh) {
            short8 a0 = *(const short8*)&As[(w << 5) + c][(kh << 5) + (quad << 3)];
            short8 a1 = *(const short8*)&As[(w << 5) + 16 + c][(kh << 5) + (quad << 3)];
#pragma unroll
            for (int n = 0; n < 4; ++n) {
                short8 b = *(const short8*)&Bs[(n << 4) + c][(kh << 5) + (quad << 3)];
                acc[0][n] = __builtin_amdgcn_mfma_f32_16x16x32_bf16(a0, b, acc[0][n], 0, 0, 0);
                acc[1][n] = __builtin_amdgcn_mfma_f32_16x16x32_bf16(a1, b, acc[1][n], 0, 0, 0);
            }
        }
        __syncthreads();
    }
#pragma unroll
    for (int mt = 0; mt < 2; ++mt) {
#pragma unroll
        for (int reg = 0; reg < 4; ++reg) {
            const int rg = r0 + (w << 5) + (mt << 4) + (quad << 2) + reg;
#pragma unroll
            for (int n = 0; n < 4; ++n) {
                const int col = c0 + (n << 4) + c;
                out[(size_t)rg * E + col] = acc[mt][n][reg] + bias[col];
            }
        }
    }
}

extern "C" void kernel_launch(void* const* d_in, const int* in_sizes, int n_in,
                              void* d_out, int out_size, void* d_ws, size_t ws_size,
                              hipStream_t stream)
{
    const float* query  = (const float*)d_in[0];
    const float* key    = (const float*)d_in[1];
    const float* value  = (const float*)d_in[2];
    const float* ipw    = (const float*)d_in[3];
    const float* ipb    = (const float*)d_in[4];
    const float* bias_k = (const float*)d_in[5];
    const float* bias_v = (const float*)d_in[6];
    const float* opw    = (const float*)d_in[7];
    const float* opb    = (const float*)d_in[8];
    const int*   kpm    = (const int*)d_in[9];

    float* out  = (float*)d_out;
    float* attn = out + (size_t)TGT * NB * E;                 // 128*512*2049 fp32

    // scratch bf16 buffers that die before the fused attention live in attn
    unsigned short* k_bf = (unsigned short*)attn;             // key converted  [32768][512]
    unsigned short* v_bf = k_bf + (size_t)16777216;           // value converted

    char* ws = (char*)d_ws;
    unsigned short* q_bf  = (unsigned short*)ws;                       // [8192][512]
    unsigned short* wi_bf = q_bf  + (size_t)4194304;                   // [3E][E]
    unsigned short* wo_bf = wi_bf + (size_t)786432;                    // [E][E]
    unsigned short* qbh   = wo_bf + (size_t)262144;                    // [bh][t][hd]
    unsigned short* kbuf  = qbh   + (size_t)4194304;                   // [bh][S1P][hd]
    unsigned short* vtbuf = kbuf  + (size_t)17301504;                  // [bh][hd][S1P]
    unsigned short* ctx   = vtbuf + (size_t)17301504;                  // [bh][t][hd]

    cvt_bf16<<<dim3(2048), 256, 0, stream>>>(query, q_bf, 524288);
    cvt_bf16<<<dim3(8192), 256, 0, stream>>>(key,   k_bf, 2097152);
    cvt_bf16<<<dim3(8192), 256, 0, stream>>>(value, v_bf, 2097152);
    cvt_bf16<<<dim3(384),  256, 0, stream>>>(ipw,   wi_bf, 98304);
    cvt_bf16<<<dim3(128),  256, 0, stream>>>(opw,   wo_bf, 32768);

    proj_all<<<dim3(8, 256, 3), 256, 0, stream>>>(q_bf, k_bf, v_bf, wi_bf, ipb,
                                                  qbh, kbuf, vtbuf);

    fill_bias<<<dim3(2300), 256, 0, stream>>>(bias_k, bias_v, kbuf, vtbuf);

    attn_fused<<<dim3(16, 128), 1024, 0, stream>>>(qbh, kbuf, vtbuf, kpm, attn, ctx);
    outproj_gemm<<<dim3(8, 64), 256, 0, stream>>>(ctx, wo_bf, opb, out);
}

// Round 11
// 992.734 us; speedup vs baseline: 1.0525x; 1.0267x over previous
//
#include <hip/hip_runtime.h>
#include <hip/hip_bf16.h>

#define E    512
#define H    8
#define HD   64
#define TGT  512
#define SRC  2048
#define S1   2049
#define S1P  2112     // padded source length (33 chunks of 64)
#define NB   16
#define BH   128
#define NCH  33
#define PW   2120     // P row stride in shorts: 4240 B = 16B-aligned, bank-uniform

typedef __attribute__((ext_vector_type(8))) short short8;
typedef __attribute__((ext_vector_type(4))) float floatx4;

__device__ __forceinline__ unsigned short f2bf(float x) {
    unsigned u = __float_as_uint(x);
    u = (u + 0x7FFF + ((u >> 16) & 1)) >> 16;   // round-to-nearest-even
    return (unsigned short)u;
}

// single fp32 -> bf16 RNE via hardware cvt
__device__ __forceinline__ unsigned short f2bf1(float x) {
    __hip_bfloat16 h = __float2bfloat16(x);
    return *(unsigned short*)&h;
}

// pack 8 fp32 -> 8 bf16 (RNE) via compiler-fused v_cvt_pk_bf16_f32
__device__ __forceinline__ int4 cvt8(const float4 f0, const float4 f1) {
    __hip_bfloat162 o[4];
    o[0] = __float22bfloat162_rn({f0.x, f0.y});
    o[1] = __float22bfloat162_rn({f0.z, f0.w});
    o[2] = __float22bfloat162_rn({f1.x, f1.y});
    o[3] = __float22bfloat162_rn({f1.z, f1.w});
    return *(int4*)o;
}

__device__ __forceinline__ void cvt_seg(const float* __restrict__ src,
    unsigned short* __restrict__ dst, const int i)
{
    const float4 f0 = ((const float4*)src)[(size_t)i * 2];
    const float4 f1 = ((const float4*)src)[(size_t)i * 2 + 1];
    ((int4*)dst)[i] = cvt8(f0, f1);
}

// ---------------------------------------------------------------------------
// single prep kernel: all 5 fp32->bf16 conversions + bias/pad fills.
// replaces 6 launches with 1 (each boundary ~3-5 us overhead + tail drain).
// segment layout (flat thread index):
//   [0, 2097152)              k cvt
//   [2097152, 4194304)        v cvt
//   [4194304, 4718592)        q cvt
//   [4718592, 5307392)        fill_bias work (588800 threads)
//   [5307392, 5405696)        wi cvt
//   [5405696, 5438464)        wo cvt
// ---------------------------------------------------------------------------
#define SEG_K   0
#define SEG_V   2097152
#define SEG_Q   4194304
#define SEG_FB  4718592
#define SEG_WI  5307392
#define SEG_WO  5405696
#define SEG_END 5438464
#define FB_BIAS 8192
#define FB_KPAD 64512                        // 128 bh * 504 int4 (63 rows * 64 hd)
#define FB_VPAD 516096                       // 128 bh * 64 hd * 63 s
__global__ __launch_bounds__(256) void prep_all(
    const float* __restrict__ query, const float* __restrict__ key,
    const float* __restrict__ value, const float* __restrict__ ipw,
    const float* __restrict__ opw, const float* __restrict__ bk,
    const float* __restrict__ bv,
    unsigned short* __restrict__ q_bf, unsigned short* __restrict__ k_bf,
    unsigned short* __restrict__ v_bf, unsigned short* __restrict__ wi_bf,
    unsigned short* __restrict__ wo_bf,
    unsigned short* __restrict__ kbuf, unsigned short* __restrict__ vtbuf)
{
    const int idx = blockIdx.x * 256 + threadIdx.x;
    if (idx >= SEG_END) return;
    if (idx < SEG_V) {
        cvt_seg(key, k_bf, idx - SEG_K);
    } else if (idx < SEG_Q) {
        cvt_seg(value, v_bf, idx - SEG_V);
    } else if (idx < SEG_FB) {
        cvt_seg(query, q_bf, idx - SEG_Q);
    } else if (idx < SEG_WI) {
        const int i = idx - SEG_FB;
        if (i < FB_BIAS) {
            const int bh = i >> 6, hd = i & 63, h = bh & 7;
            kbuf[((size_t)bh * S1P + SRC) * HD + hd] = f2bf(bk[h * HD + hd]);
            vtbuf[((size_t)bh * HD + hd) * S1P + SRC] = f2bf(bv[h * HD + hd]);
        } else if (i < FB_BIAS + FB_KPAD) {
            const int j = i - FB_BIAS;
            const int bh = j / 504, o = j % 504;
            const int4 z = {0, 0, 0, 0};
            ((int4*)&kbuf[((size_t)bh * S1P + S1) * HD])[o] = z;
        } else {
            const int j = i - FB_BIAS - FB_KPAD;
            const int bh = j / 4032, r = j % 4032;
            const int hd = r / 63, s = S1 + r % 63;
            vtbuf[((size_t)bh * HD + hd) * S1P + s] = 0;
        }
    } else if (idx < SEG_WO) {
        cvt_seg(ipw, wi_bf, idx - SEG_WI);
    } else {
        cvt_seg(opw, wo_bf, idx - SEG_WO);
    }
}

// ---------------------------------------------------------------------------
// merged in-projection for q/k/v, flat grid (no early-exit no-op blocks):
//   y <  64 : q -> qbh [bh][t][hd], scaled 0.125
//   y < 320 : k -> kbuf [bh][s][hd] (ld = S1P)
//   else    : v -> vtbuf [bh][hd][s] TRANSPOSED via LDS re-stage epilogue
// ---------------------------------------------------------------------------
__global__ __launch_bounds__(256) void proj_all(
    const unsigned short* __restrict__ q_bf, const unsigned short* __restrict__ k_bf,
    const unsigned short* __restrict__ v_bf, const unsigned short* __restrict__ wi,
    const float* __restrict__ ipb,
    unsigned short* __restrict__ qbh, unsigned short* __restrict__ kbuf,
    unsigned short* __restrict__ vtbuf)
{
    const int y = blockIdx.y;
    const int z  = (y < 64) ? 0 : (y < 320) ? 1 : 2;
    const int by = (y < 64) ? y : (y < 320) ? y - 64 : y - 320;
    __shared__ __align__(16) unsigned short As[128][72];
    __shared__ __align__(16) unsigned short Bs[64][72];
    const unsigned short* X = (z == 0) ? q_bf : (z == 1) ? k_bf : v_bf;
    const unsigned short* W = wi + (size_t)z * 262144;
    const float* bias = ipb + z * E;
    const int tid  = threadIdx.x;
    const int c0   = blockIdx.x << 6;
    const int r0   = by << 7;
    const int w    = tid >> 6, lane = tid & 63, c = lane & 15, quad = lane >> 4;
    floatx4 acc[2][4] = {};
    for (int k0 = 0; k0 < E; k0 += 64) {
#pragma unroll
        for (int i = 0; i < 4; ++i) {
            const int idx = tid + (i << 8);
            const int r = idx >> 3, q = (idx & 7) << 3;
            *(int4*)&As[r][q] = *(const int4*)&X[(size_t)(r0 + r) * E + k0 + q];
        }
#pragma unroll
        for (int i = 0; i < 2; ++i) {
            const int idx = tid + (i << 8);
            const int r = idx >> 3, q = (idx & 7) << 3;
            *(int4*)&Bs[r][q] = *(const int4*)&W[(size_t)(c0 + r) * E + k0 + q];
        }
        __syncthreads();
#pragma unroll
        for (int kh = 0; kh < 2; ++kh) {
            short8 a0 = *(const short8*)&As[(w << 5) + c][(kh << 5) + (quad << 3)];
            short8 a1 = *(const short8*)&As[(w << 5) + 16 + c][(kh << 5) + (quad << 3)];
#pragma unroll
            for (int n = 0; n < 4; ++n) {
                short8 b = *(const short8*)&Bs[(n << 4) + c][(kh << 5) + (quad << 3)];
                acc[0][n] = __builtin_amdgcn_mfma_f32_16x16x32_bf16(a0, b, acc[0][n], 0, 0, 0);
                acc[1][n] = __builtin_amdgcn_mfma_f32_16x16x32_bf16(a1, b, acc[1][n], 0, 0, 0);
            }
        }
        __syncthreads();
    }
    if (z == 2) {
        // transposed epilogue: acc tile -> As (bf16), then each thread gathers
        // 8 consecutive s for one (b,hd) -> single int4 store
        const int h = c0 >> 6;
#pragma unroll
        for (int mt = 0; mt < 2; ++mt) {
#pragma unroll
            for (int reg = 0; reg < 4; ++reg) {
                const int local = (w << 5) + (mt << 4) + (quad << 2) + reg;
#pragma unroll
                for (int n = 0; n < 4; ++n) {
                    const int hd = (n << 4) + c;
                    As[local][hd] = f2bf1(acc[mt][n][reg] + bias[c0 + hd]);
                }
            }
        }
        __syncthreads();
        const int s0v = by << 3;
#pragma unroll
        for (int i = 0; i < 4; ++i) {
            const int idx = tid + (i << 8);
            const int b = idx & 15, hd = idx >> 4;
            unsigned short tmp[8];
#pragma unroll
            for (int j = 0; j < 8; ++j) tmp[j] = As[(j << 4) + b][hd];
            *(int4*)&vtbuf[((size_t)(b * H + h) * HD + hd) * S1P + s0v] = *(int4*)tmp;
        }
        return;
    }
    unsigned short* Y = (z == 0) ? qbh : kbuf;
    const int ld = (z == 0) ? TGT : S1P;
    const float scale = (z == 0) ? 0.125f : 1.0f;
#pragma unroll
    for (int mt = 0; mt < 2; ++mt) {
#pragma unroll
        for (int reg = 0; reg < 4; ++reg) {
            const int rg = r0 + (w << 5) + (mt << 4) + (quad << 2) + reg;
            const int t = rg >> 4, b = rg & 15;
#pragma unroll
            for (int n = 0; n < 4; ++n) {
                const int col = c0 + (n << 4) + c;
                const int h = col >> 6, hd = col & 63;
                const float v = (acc[mt][n][reg] + bias[col]) * scale;
                Y[((size_t)(b * H + h) * ld + t) * HD + hd] = f2bf1(v);
            }
        }
    }
}

// ---------------------------------------------------------------------------
// Fused single-pass attention, QBLK=32 (R10 structure, best measured).
// 1024 threads / 16 waves, P resident in 135.7 KB LDS, 1 block/CU.
// Phase-1 change: both chunk loads (w, w+16) issued before either compute,
// overlapping the two global-load latencies instead of serializing them.
// ---------------------------------------------------------------------------
__global__ __launch_bounds__(1024) void attn_fused(
    const unsigned short* __restrict__ qbh,
    const unsigned short* __restrict__ kbuf,
    const unsigned short* __restrict__ vtbuf,
    const int* __restrict__ kpm,
    float* __restrict__ attn, unsigned short* __restrict__ ctx)
{
    __shared__ __align__(16) unsigned short P[32][PW];   // 135.68 KB
    __shared__ float cpart[32][68];                      // 8.70 KB
    __shared__ float sums[16][32];                       // 2 KB
    __shared__ float linv[32];
    const int tid = threadIdx.x;
    const int t0  = blockIdx.x << 5;
    const int bh  = blockIdx.y;
    const int bb  = bh >> 3;
    const int w = tid >> 6, lane = tid & 63, c = lane & 15, quad = lane >> 4;

    // Q A-fragments for rows t0..t0+15 (qa) and t0+16..t0+31 (qb)
    const unsigned short* qr = &qbh[((size_t)bh * TGT + t0 + c) * HD + (quad << 3)];
    short8 qa0 = *(const short8*)qr;
    short8 qa1 = *(const short8*)(qr + 32);
    const unsigned short* qr2 = qr + (size_t)16 * HD;
    short8 qb0 = *(const short8*)qr2;
    short8 qb1 = *(const short8*)(qr2 + 32);

#define LOADK(B0, B1, M, CH) do {                                               \
        const unsigned short* kb_ = &kbuf[((size_t)bh * S1P + ((CH) << 6)) * HD]; \
        _Pragma("unroll")                                                       \
        for (int n_ = 0; n_ < 4; ++n_) {                                        \
            const unsigned short* kr_ = kb_ + ((n_ << 4) + c) * HD + (quad << 3); \
            B0[n_] = *(const short8*)kr_;                                       \
            B1[n_] = *(const short8*)(kr_ + 32);                                \
        }                                                                       \
        _Pragma("unroll")                                                       \
        for (int n_ = 0; n_ < 4; ++n_) {                                        \
            const int s_ = ((CH) << 6) + (n_ << 4) + c;                         \
            M[n_] = (s_ < SRC) ? (kpm[bb * SRC + s_] ? 3e38f : 0.f)             \
                               : ((s_ == SRC) ? 0.f : 3e38f);                   \
        }                                                                       \
    } while (0)

#define QK2(B0, B1, M, CH) do {                                                 \
        const int s0_ = (CH) << 6;                                              \
        floatx4 sc_[4] = {};                                                    \
        _Pragma("unroll")                                                       \
        for (int n_ = 0; n_ < 4; ++n_) {                                        \
            sc_[n_] = __builtin_amdgcn_mfma_f32_16x16x32_bf16(qa0, B0[n_], sc_[n_], 0, 0, 0); \
            sc_[n_] = __builtin_amdgcn_mfma_f32_16x16x32_bf16(qa1, B1[n_], sc_[n_], 0, 0, 0); \
        }                                                                       \
        _Pragma("unroll")                                                       \
        for (int n_ = 0; n_ < 4; ++n_) {                                        \
            _Pragma("unroll")                                                   \
            for (int rg_ = 0; rg_ < 4; ++rg_) {                                 \
                const float p_ = __expf(sc_[n_][rg_] - M[n_]);                  \
                rs0[rg_] += p_;                                                 \
                P[(quad << 2) + rg_][s0_ + (n_ << 4) + c] = f2bf1(p_);          \
            }                                                                   \
        }                                                                       \
        floatx4 sd_[4] = {};                                                    \
        _Pragma("unroll")                                                       \
        for (int n_ = 0; n_ < 4; ++n_) {                                        \
            sd_[n_] = __builtin_amdgcn_mfma_f32_16x16x32_bf16(qb0, B0[n_], sd_[n_], 0, 0, 0); \
            sd_[n_] = __builtin_amdgcn_mfma_f32_16x16x32_bf16(qb1, B1[n_], sd_[n_], 0, 0, 0); \
        }                                                                       \
        _Pragma("unroll")                                                       \
        for (int n_ = 0; n_ < 4; ++n_) {                                        \
            _Pragma("unroll")                                                   \
            for (int rg_ = 0; rg_ < 4; ++rg_) {                                 \
                const float p_ = __expf(sd_[n_][rg_] - M[n_]);                  \
                rs1[rg_] += p_;                                                 \
                P[16 + (quad << 2) + rg_][s0_ + (n_ << 4) + c] = f2bf1(p_);     \
            }                                                                   \
        }                                                                       \
    } while (0)

    // ---- phase 1: QK^T + exp, 33 chunks over 16 waves; both chunk loads
    // issued up-front so their latencies overlap ----
    float rs0[4] = {0.f, 0.f, 0.f, 0.f};
    float rs1[4] = {0.f, 0.f, 0.f, 0.f};
    short8 ka0[4], ka1[4], kc0[4], kc1[4];
    float ma[4], mc[4];
    LOADK(ka0, ka1, ma, w);
    LOADK(kc0, kc1, mc, w + 16);
    QK2(ka0, ka1, ma, w);
    QK2(kc0, kc1, mc, w + 16);
    if (w == 0) {
        LOADK(ka0, ka1, ma, 32);
        QK2(ka0, ka1, ma, 32);
    }

    // ---- phase 2: row-sum reduction (over c lanes, then over 16 waves) ----
#pragma unroll
    for (int reg = 0; reg < 4; ++reg) {
        float v0s = rs0[reg], v1s = rs1[reg];
        v0s += __shfl_xor(v0s, 1); v0s += __shfl_xor(v0s, 2);
        v0s += __shfl_xor(v0s, 4); v0s += __shfl_xor(v0s, 8);
        v1s += __shfl_xor(v1s, 1); v1s += __shfl_xor(v1s, 2);
        v1s += __shfl_xor(v1s, 4); v1s += __shfl_xor(v1s, 8);
        rs0[reg] = v0s; rs1[reg] = v1s;
    }
    if (c == 0) {
#pragma unroll
        for (int reg = 0; reg < 4; ++reg) {
            sums[w][(quad << 2) + reg]      = rs0[reg];
            sums[w][16 + (quad << 2) + reg] = rs1[reg];
        }
    }
    __syncthreads();
    if (tid < 32) {
        float s = 0.f;
#pragma unroll
        for (int i = 0; i < 16; ++i) s += sums[i][tid];
        linv[tid] = 1.0f / s;
    }
    __syncthreads();

    // ---- phase 3a: PV. wave -> (row-half rh, hd-slice hs, K-half kh2) ----
    const int rh = w >> 3, hs = (w >> 1) & 3, kh2 = w & 1;
    const int base = kh2 * 1056;
    const unsigned short* vrow = &vtbuf[((size_t)bh * HD + (hs << 4) + c) * S1P + base];
#define LV(U) (*(const short8*)&vrow[((U) << 5) + (quad << 3)])
#define LP(U) (*(const short8*)&P[(rh << 4) + c][base + ((U) << 5) + (quad << 3)])
    floatx4 ca0 = {}, ca1 = {};
    short8 vt = LV(32);
    short8 v0 = LV(0), v1 = LV(1), v2 = LV(2), v3 = LV(3);
#pragma unroll
    for (int u = 0; u < 32; u += 4) {
        ca0 = __builtin_amdgcn_mfma_f32_16x16x32_bf16(LP(u),     v0, ca0, 0, 0, 0);
        ca1 = __builtin_amdgcn_mfma_f32_16x16x32_bf16(LP(u + 1), v1, ca1, 0, 0, 0);
        if (u < 28) { v0 = LV(u + 4); v1 = LV(u + 5); }
        ca0 = __builtin_amdgcn_mfma_f32_16x16x32_bf16(LP(u + 2), v2, ca0, 0, 0, 0);
        ca1 = __builtin_amdgcn_mfma_f32_16x16x32_bf16(LP(u + 3), v3, ca1, 0, 0, 0);
        if (u < 28) { v2 = LV(u + 6); v3 = LV(u + 7); }
    }
    ca0 = __builtin_amdgcn_mfma_f32_16x16x32_bf16(LP(32), vt, ca0, 0, 0, 0);
    if (kh2 == 1) {
#pragma unroll
        for (int reg = 0; reg < 4; ++reg)
            cpart[(rh << 4) + (quad << 2) + reg][(hs << 4) + c] = ca0[reg] + ca1[reg];
    }
    __syncthreads();
    if (kh2 == 0) {
#pragma unroll
        for (int reg = 0; reg < 4; ++reg) {
            const int row = (rh << 4) + (quad << 2) + reg;
            const float v = (ca0[reg] + ca1[reg] + cpart[row][(hs << 4) + c]) * linv[row];
            ctx[((size_t)bh * TGT + t0 + row) * HD + (hs << 4) + c] = f2bf1(v);
        }
    }

    // ---- phase 3b: normalized fp32 attn stores; wave w owns cols
    // [128w, 128w+128); each lane reads 2 P values per b32 LDS read. ----
    {
        const int s0 = w << 7;
#pragma unroll
        for (int r = 0; r < 32; ++r) {
            const unsigned pk = *(const unsigned*)&P[r][s0 + (lane << 1)];
            const float li = linv[r];
            const size_t a = ((size_t)bh * TGT + t0 + r) * S1 + s0 + (lane << 1);
            attn[a]     = __uint_as_float((pk & 0xFFFFu) << 16) * li;
            attn[a + 1] = __uint_as_float(pk & 0xFFFF0000u) * li;
        }
    }
    if (w == 15 && lane < 32) {   // last real column s == 2048
        const float p = __uint_as_float((unsigned)P[lane][2048] << 16) * linv[lane];
        attn[((size_t)bh * TGT + t0 + lane) * S1 + 2048] = p;
    }
#undef LOADK
#undef QK2
#undef LV
#undef LP
}

// ---------------------------------------------------------------------------
// out-projection: out[r][e] = ctx_row(r) . W[e][:] + bias[e]  (fp32 out)
// ---------------------------------------------------------------------------
__global__ __launch_bounds__(256) void outproj_gemm(const unsigned short* __restrict__ ctx,
    const unsigned short* __restrict__ W, const float* __restrict__ bias,
    float* __restrict__ out)
{
    __shared__ __align__(16) unsigned short As[128][72];
    __shared__ __align__(16) unsigned short Bs[64][72];
    const int tid = threadIdx.x;
    const int c0  = blockIdx.x << 6;
    const int r0  = blockIdx.y << 7;
    const int w   = tid >> 6, lane = tid & 63, c = lane & 15, quad = lane >> 4;
    floatx4 acc[2][4] = {};
    for (int k0 = 0; k0 < E; k0 += 64) {
        const int h = k0 >> 6;
#pragma unroll
        for (int i = 0; i < 4; ++i) {
            const int idx = tid + (i << 8);
            const int r = idx >> 3, q = (idx & 7) << 3;
            const int rg = r0 + r, t = rg >> 4, b = rg & 15;
            *(int4*)&As[r][q] = *(const int4*)&ctx[((size_t)(b * H + h) * TGT + t) * HD + q];
        }
#pragma unroll
        for (int i = 0; i < 2; ++i) {
            const int idx = tid + (i << 8);
            const int r = idx >> 3, q = (idx & 7) << 3;
            *(int4*)&Bs[r][q] = *(const int4*)&W[(size_t)(c0 + r) * E + k0 + q];
        }
        __syncthreads();
#pragma unroll
        for (int kh = 0; kh < 2; ++kh) {
            short8 a0 = *(const short8*)&As[(w << 5) + c][(kh << 5) + (quad << 3)];
            short8 a1 = *(const short8*)&As[(w << 5) + 16 + c][(kh << 5) + (quad << 3)];
#pragma unroll
            for (int n = 0; n < 4; ++n) {
                short8 b = *(const short8*)&Bs[(n << 4) + c][(kh << 5) + (quad << 3)];
                acc[0][n] = __builtin_amdgcn_mfma_f32_16x16x32_bf16(a0, b, acc[0][n], 0, 0, 0);
                acc[1][n] = __builtin_amdgcn_mfma_f32_16x16x32_bf16(a1, b, acc[1][n], 0, 0, 0);
            }
        }
        __syncthreads();
    }
#pragma unroll
    for (int mt = 0; mt < 2; ++mt) {
#pragma unroll
        for (int reg = 0; reg < 4; ++reg) {
            const int rg = r0 + (w << 5) + (mt << 4) + (quad << 2) + reg;
#pragma unroll
            for (int n = 0; n < 4; ++n) {
                const int col = c0 + (n << 4) + c;
                out[(size_t)rg * E + col] = acc[mt][n][reg] + bias[col];
            }
        }
    }
}

extern "C" void kernel_launch(void* const* d_in, const int* in_sizes, int n_in,
                              void* d_out, int out_size, void* d_ws, size_t ws_size,
                              hipStream_t stream)
{
    const float* query  = (const float*)d_in[0];
    const float* key    = (const float*)d_in[1];
    const float* value  = (const float*)d_in[2];
    const float* ipw    = (const float*)d_in[3];
    const float* ipb    = (const float*)d_in[4];
    const float* bias_k = (const float*)d_in[5];
    const float* bias_v = (const float*)d_in[6];
    const float* opw    = (const float*)d_in[7];
    const float* opb    = (const float*)d_in[8];
    const int*   kpm    = (const int*)d_in[9];

    float* out  = (float*)d_out;
    float* attn = out + (size_t)TGT * NB * E;                 // 128*512*2049 fp32

    // scratch bf16 buffers that die before the fused attention live in attn
    unsigned short* k_bf = (unsigned short*)attn;             // key converted  [32768][512]
    unsigned short* v_bf = k_bf + (size_t)16777216;           // value converted

    char* ws = (char*)d_ws;
    unsigned short* q_bf  = (unsigned short*)ws;                       // [8192][512]
    unsigned short* wi_bf = q_bf  + (size_t)4194304;                   // [3E][E]
    unsigned short* wo_bf = wi_bf + (size_t)786432;                    // [E][E]
    unsigned short* qbh   = wo_bf + (size_t)262144;                    // [bh][t][hd]
    unsigned short* kbuf  = qbh   + (size_t)4194304;                   // [bh][S1P][hd]
    unsigned short* vtbuf = kbuf  + (size_t)17301504;                  // [bh][hd][S1P]
    unsigned short* ctx   = vtbuf + (size_t)17301504;                  // [bh][t][hd]

    prep_all<<<dim3(21244), 256, 0, stream>>>(query, key, value, ipw, opw,
                                              bias_k, bias_v,
                                              q_bf, k_bf, v_bf, wi_bf, wo_bf,
                                              kbuf, vtbuf);

    proj_all<<<dim3(8, 576), 256, 0, stream>>>(q_bf, k_bf, v_bf, wi_bf, ipb,
                                               qbh, kbuf, vtbuf);

    attn_fused<<<dim3(16, 128), 1024, 0, stream>>>(qbh, kbuf, vtbuf, kpm, attn, ctx);
    outproj_gemm<<<dim3(8, 64), 256, 0, stream>>>(ctx, wo_bf, opb, out);
}